// Round 4
// baseline (622.173 us; speedup 1.0000x reference)
//
#include <hip/hip_runtime.h>
#include <hip/hip_bf16.h>

#define B_ 4
#define H_ 16
#define SQ 2048
#define SKV 2048
#define D_ 128
#define BH (B_*H_)
#define BM 256
#define BN 32
#define NITER (SKV/BN)      // 64

typedef __attribute__((ext_vector_type(8))) short bf16x8;
typedef __attribute__((ext_vector_type(4))) float f32x4;

__device__ inline unsigned short f2bf(float f) {
    union { float f; unsigned u; } x{f};
    unsigned r = x.u + 0x7fffu + ((x.u >> 16) & 1u);
    return (unsigned short)(r >> 16);
}

#if defined(__has_builtin) && __has_builtin(__builtin_amdgcn_cvt_pk_bf16_f32)
#define PKBF16(a,b) ({ auto _r = __builtin_amdgcn_cvt_pk_bf16_f32((a),(b)); \
                       unsigned _u; __builtin_memcpy(&_u, &_r, 4); _u; })
#else
#define PKBF16(a,b) ((unsigned)f2bf(a) | ((unsigned)f2bf(b) << 16))
#endif

// async global->LDS, 16B/lane; LDS dest = wave-uniform base + lane*16
__device__ inline void gl_lds16(const short* g, short* l) {
    __builtin_amdgcn_global_load_lds((const __attribute__((address_space(1))) unsigned*)g,
                                     (__attribute__((address_space(3))) unsigned*)l,
                                     16, 0, 0);
}

// ---------------- merged prepass: K cvt (bx<8192) | V transpose (bx>=8192) --
__global__ __launch_bounds__(256) void prep(const float* __restrict__ kin,
                                            const float* __restrict__ vin,
                                            short* __restrict__ kbf,
                                            short* __restrict__ vtg) {
    __shared__ unsigned tile[128 * 33];   // dword = (kv even, kv odd) bf16 pair
    int bx = blockIdx.x, tid = threadIdx.x;
    if (bx < 8192) {
        const float4* s = (const float4*)kin;
        uint2* d = (uint2*)kbf;
        int i = bx * 256 + tid;
        const int HALF = (BH * SKV * D_ / 4) / 2;
#pragma unroll
        for (int h = 0; h < 2; ++h) {
            int j = i + h * HALF;
            float4 a = s[j];
            d[j] = make_uint2(PKBF16(a.x, a.y), PKBF16(a.z, a.w));
        }
    } else {
        int bx2 = bx - 8192;
        int bh = bx2 >> 5;
        int t0 = (bx2 & 31) * 64;
        int kvp = tid >> 4, dc = tid & 15;
        // P1: read kv-row pairs coalesced, pack cross-row dwords, b32 LDS writes
#pragma unroll
        for (int s = 0; s < 2; ++s) {
            int pi = kvp + s * 16;                       // kv-pair index 0..31
            const float* r0 = vin + ((size_t)bh * SKV + t0 + 2 * pi) * D_ + dc * 8;
            const float* r1 = r0 + D_;
            float4 a0 = *(const float4*)r0, b0 = *(const float4*)(r0 + 4);
            float4 a1 = *(const float4*)r1, b1 = *(const float4*)(r1 + 4);
            unsigned* tb = &tile[(dc * 8) * 33 + pi];
            tb[0 * 33] = PKBF16(a0.x, a1.x);
            tb[1 * 33] = PKBF16(a0.y, a1.y);
            tb[2 * 33] = PKBF16(a0.z, a1.z);
            tb[3 * 33] = PKBF16(a0.w, a1.w);
            tb[4 * 33] = PKBF16(b0.x, b1.x);
            tb[5 * 33] = PKBF16(b0.y, b1.y);
            tb[6 * 33] = PKBF16(b0.z, b1.z);
            tb[7 * 33] = PKBF16(b0.w, b1.w);
        }
        __syncthreads();
        // P2: b128 LDS reads (uniform bank spread), 128B-segment global stores
        int drow = tid >> 3, kvc = tid & 7;
#pragma unroll
        for (int ss = 0; ss < 4; ++ss) {
            int d = drow + ss * 32;
            uint4 w = *(const uint4*)&tile[d * 33 + kvc * 4];
            *(uint4*)(vtg + ((size_t)bh * D_ + d) * SKV + t0 + kvc * 8) = w;
        }
    }
}

// ---------------- flash attention: 64 q-rows/wave, BM=256, dbuf BN=32 ------
// Ksh: [32 kv][128 d halves], 16 chunks of 8; chunk c at pos c^(row&15)
// Vsh: [128 d][32 kv halves], 4 chunks of 8;  chunk c at pos c^((row>>1)&3)
// Psh: per-wave [64 q][32 kv], stride 40 halves
__global__ __launch_bounds__(256, 2) void fa_kernel(const float* __restrict__ q,
                                                    const short* __restrict__ kbf,
                                                    const short* __restrict__ vtg,
                                                    float* __restrict__ out) {
    __shared__ short Ksh[2 * 32 * 128];   // 16 KB
    __shared__ short Vsh[2 * 128 * 32];   // 16 KB
    __shared__ short Psh[4 * 64 * 40];    // 20 KB  -> 52 KB total

    const int tid = threadIdx.x;
    const int wave = tid >> 6;
    const int lane = tid & 63;
    const int l16 = lane & 15;
    const int quad = lane >> 4;

    const int bx = blockIdx.x;
    const int qt = bx & 7;          // SQ/BM = 8
    const int bh = bx >> 3;
    const int qrow0 = qt * BM + wave * 64;

    const float cscale = 1.4426950408889634f * 0.08838834764831845f; // log2e/sqrt(128)

    // Q fragments (B-operand): lane n=l16, k = ks*32 + quad*8 + j
    bf16x8 qf[4][4];
#pragma unroll
    for (int mt = 0; mt < 4; ++mt) {
        int row = qrow0 + mt * 16 + l16;
        const float* qp = q + ((size_t)bh * SQ + row) * D_ + quad * 8;
#pragma unroll
        for (int ks = 0; ks < 4; ++ks) {
            const float* p = qp + ks * 32;
            float4 a = *(const float4*)p;
            float4 b = *(const float4*)(p + 4);
            union { unsigned u[4]; bf16x8 v; } f;
            f.u[0] = PKBF16(a.x * cscale, a.y * cscale);
            f.u[1] = PKBF16(a.z * cscale, a.w * cscale);
            f.u[2] = PKBF16(b.x * cscale, b.y * cscale);
            f.u[3] = PKBF16(b.z * cscale, b.w * cscale);
            qf[mt][ks] = f.v;
        }
    }

    f32x4 oacc[8][4];
#pragma unroll
    for (int dt = 0; dt < 8; ++dt)
#pragma unroll
        for (int mt = 0; mt < 4; ++mt) oacc[dt][mt] = (f32x4)0.f;
    float lsum[4] = {0.f, 0.f, 0.f, 0.f};

    // staging addresses (per-lane swizzle encoded in GLOBAL addr; LDS base uniform)
    const short* kbase = kbf + (size_t)bh * SKV * D_;
    const short* vbase = vtg + (size_t)bh * D_ * SKV;
    const int kr = wave * 4 + (lane >> 4);                 // rows kr, kr+16
    const int kc = (lane & 15) ^ kr;                       // (row&15)==kr both s
    const short* kg = kbase + kr * 128 + kc * 8;           // +s*2048, +it*4096
    const int vrow = wave * 16 + (lane >> 2);              // +s*64
    const int vc = (lane & 3) ^ ((lane >> 3) & 3);
    const short* vg = vbase + (size_t)vrow * SKV + vc * 8; // +s*64*SKV, +it*32
    short* const klb = Ksh + wave * 512;                   // +s*2048, +buf
    short* const vlb = Vsh + wave * 512;
    short* const pwav = Psh + wave * 2560;

    auto stage = [&](int it, int bufo) {
        const short* kgi = kg + it * (BN * D_);
        const short* vgi = vg + it * BN;
#pragma unroll
        for (int s = 0; s < 2; ++s) {
            gl_lds16(kgi + s * 2048, klb + bufo + s * 2048);
            gl_lds16(vgi + (size_t)s * 64 * SKV, vlb + bufo + s * 2048);
        }
    };

    auto compute = [&](int bufo) {
#pragma unroll
        for (int kt = 0; kt < 2; ++kt) {
            f32x4 sacc[4];
#pragma unroll
            for (int mt = 0; mt < 4; ++mt) sacc[mt] = (f32x4)0.f;
#pragma unroll
            for (int ks = 0; ks < 4; ++ks) {
                bf16x8 kf = *(const bf16x8*)&Ksh[bufo + (kt * 16 + l16) * 128 + (((ks * 4 + quad) ^ l16) << 3)];
#pragma unroll
                for (int mt = 0; mt < 4; ++mt)
                    sacc[mt] = __builtin_amdgcn_mfma_f32_16x16x32_bf16(kf, qf[mt][ks], sacc[mt], 0, 0, 0);
            }
#pragma unroll
            for (int mt = 0; mt < 4; ++mt) {
                float p0 = __builtin_amdgcn_exp2f(sacc[mt][0]);
                float p1 = __builtin_amdgcn_exp2f(sacc[mt][1]);
                float p2 = __builtin_amdgcn_exp2f(sacc[mt][2]);
                float p3 = __builtin_amdgcn_exp2f(sacc[mt][3]);
                lsum[mt] += (p0 + p1) + (p2 + p3);
                *(uint2*)&pwav[(mt * 16 + l16) * 40 + kt * 16 + quad * 4] =
                    make_uint2(PKBF16(p0, p1), PKBF16(p2, p3));
            }
        }
        // PV: O^T += V^T·P^T (wave-private P; same-wave DS ordering)
        bf16x8 pa[4];
#pragma unroll
        for (int mt = 0; mt < 4; ++mt)
            pa[mt] = *(const bf16x8*)&pwav[(mt * 16 + l16) * 40 + quad * 8];
#pragma unroll
        for (int dt = 0; dt < 8; ++dt) {
            bf16x8 vf = *(const bf16x8*)&Vsh[bufo + (dt * 16 + l16) * 32 + ((quad ^ ((l16 >> 1) & 3)) << 3)];
#pragma unroll
            for (int mt = 0; mt < 4; ++mt)
                oacc[dt][mt] = __builtin_amdgcn_mfma_f32_16x16x32_bf16(vf, pa[mt], oacc[dt][mt], 0, 0, 0);
        }
    };

    stage(0, 0);
    for (int it = 0; it < NITER; it += 2) {
        __syncthreads();                 // drains buf0 loads (issued last round)
        stage(it + 1, 4096);             // prefetch into buf1 (flies over compute)
        compute(0);
        __syncthreads();                 // drains buf1 loads; buf0 reads done
        if (it + 2 < NITER) stage(it + 2, 0);
        compute(4096);
    }

    // epilogue: reduce partial row sums over quads, scale, b128 stores
#pragma unroll
    for (int mt = 0; mt < 4; ++mt) {
        lsum[mt] += __shfl_xor(lsum[mt], 16);
        lsum[mt] += __shfl_xor(lsum[mt], 32);
    }
#pragma unroll
    for (int mt = 0; mt < 4; ++mt) {
        float rl = 1.0f / lsum[mt];
        float* op = out + ((size_t)bh * SQ + qrow0 + mt * 16 + l16) * D_ + quad * 4;
#pragma unroll
        for (int dt = 0; dt < 8; ++dt) {
            f32x4 v = oacc[dt][mt] * rl;
            *(f32x4*)(op + dt * 16) = v;
        }
    }
}

extern "C" void kernel_launch(void* const* d_in, const int* in_sizes, int n_in,
                              void* d_out, int out_size, void* d_ws, size_t ws_size,
                              hipStream_t stream) {
    const float* q = (const float*)d_in[0];
    const float* k = (const float*)d_in[1];
    const float* v = (const float*)d_in[2];
    float* out = (float*)d_out;

    short* kbf = (short*)d_ws;                    // 33.55 MB bf16 K
    short* vtg = kbf + (size_t)BH * SKV * D_;     // 33.55 MB bf16 V^T

    prep<<<8192 + 2048, 256, 0, stream>>>(k, v, kbf, vtg);
    fa_kernel<<<BH * (SQ / BM), 256, 0, stream>>>(q, kbf, vtg, out);
}